// Round 1
// baseline (313.108 us; speedup 1.0000x reference)
//
#include <hip/hip_runtime.h>

namespace {

constexpr int BATCH = 32;
constexpr int CIN   = 64;
constexpr int HW    = 56;
constexpr int K     = 128;
constexpr int SP    = HW * HW;   // 3136 spatial positions per image
constexpr int KPT   = 4;         // output channels per thread
constexpr int BLK   = 256;

__global__ __launch_bounds__(BLK)
void conv3x3_kernel(const float* __restrict__ x,
                    const float* __restrict__ w,
                    const float* __restrict__ off,
                    float* __restrict__ out)
{
    const int s  = blockIdx.x * BLK + threadIdx.x;   // in [0, BATCH*SP)
    const int b  = s / SP;
    const int sp = s - b * SP;
    const int y  = sp / HW;
    const int xx = sp - y * HW;
    const int k0 = blockIdx.y * KPT;

    // Clamped column indices + boundary masks, computed once per thread.
    const int   xm1 = (xx > 0)      ? xx - 1 : 0;
    const int   xp1 = (xx < HW - 1) ? xx + 1 : HW - 1;
    const float m0  = (xx > 0)      ? 1.f : 0.f;
    const float m2  = (xx < HW - 1) ? 1.f : 0.f;

    int   ro[3];        // clamped row offsets
    float msk[3][3];    // per-tap validity masks
    #pragma unroll
    for (int ky = 0; ky < 3; ++ky) {
        const int  yy = y + ky - 1;
        const bool ok = (unsigned)yy < (unsigned)HW;
        const float rm = ok ? 1.f : 0.f;
        ro[ky] = (ok ? yy : 0) * HW;
        msk[ky][0] = rm * m0;
        msk[ky][1] = rm;
        msk[ky][2] = rm * m2;
    }

    float acc[KPT];
    #pragma unroll
    for (int i = 0; i < KPT; ++i) acc[i] = 0.f;

    const float* xb = x + b * (CIN * SP);

    for (int c = 0; c < CIN; ++c) {
        const float* xc = xb + c * SP;
        #pragma unroll
        for (int ky = 0; ky < 3; ++ky) {
            const float* xr = xc + ro[ky];
            // Clamped loads are always in-bounds; masks zero the padded taps.
            const float v0 = xr[xm1] * msk[ky][0];
            const float v1 = xr[xx]  * msk[ky][1];
            const float v2 = xr[xp1] * msk[ky][2];
            const int wi = c * 9 + ky * 3;
            #pragma unroll
            for (int kk = 0; kk < KPT; ++kk) {
                // k0+kk and wi are wave-uniform -> scalar loads (SGPR operands).
                const float* wr = w + (k0 + kk) * (CIN * 9) + wi;
                acc[kk] = fmaf(v0, wr[0], acc[kk]);
                acc[kk] = fmaf(v1, wr[1], acc[kk]);
                acc[kk] = fmaf(v2, wr[2], acc[kk]);
            }
        }
    }

    #pragma unroll
    for (int kk = 0; kk < KPT; ++kk) {
        out[(b * K + k0 + kk) * SP + sp] = acc[kk] + off[k0 + kk];
    }
}

} // namespace

extern "C" void kernel_launch(void* const* d_in, const int* in_sizes, int n_in,
                              void* d_out, int out_size, void* d_ws, size_t ws_size,
                              hipStream_t stream)
{
    const float* x   = (const float*)d_in[0];
    const float* w   = (const float*)d_in[1];
    const float* off = (const float*)d_in[2];
    float* out = (float*)d_out;

    dim3 grid((BATCH * SP) / BLK, K / KPT);   // 392 x 32 blocks
    conv3x3_kernel<<<grid, dim3(BLK, 1, 1), 0, stream>>>(x, w, off, out);
}

// Round 2
// 76.517 us; speedup vs baseline: 4.0920x; 4.0920x over previous
//
#include <hip/hip_runtime.h>
#include <hip/hip_bf16.h>

namespace {

using frag_t   = __attribute__((ext_vector_type(8))) short;          // 8 bf16 = 4 VGPR
using f32x4    = __attribute__((ext_vector_type(4))) float;          // MFMA acc
using ushort4_t= __attribute__((ext_vector_type(4))) unsigned short; // 8B LDS write

constexpr int BATCH = 32;
constexpr int CIN   = 64;
constexpr int HWD   = 56;
constexpr int KOUT  = 128;
constexpr int SP    = HWD * HWD;        // 3136
constexpr int KD    = 9 * CIN;          // 576 (kk = tap*64 + c)
constexpr int BN    = 128;              // spatial tile per block
constexpr int HALO  = 57;               // max |shift| = 56+1
constexpr int NEXT  = BN + 2 * HALO;    // 242 staged rows
constexpr int NTILES= (SP + BN - 1)/BN; // 25

__device__ inline unsigned short f2bf(float f) {
    __hip_bfloat16 h = __float2bfloat16(f);
    return __builtin_bit_cast(unsigned short, h);
}

// ---- weight repack: w[k][c][ky][kx] f32 -> Wp[k][t*64+c] bf16 (t=ky*3+kx) ----
__global__ __launch_bounds__(256)
void wconv_kernel(const float* __restrict__ w, unsigned short* __restrict__ wp)
{
    int idx = blockIdx.x * 256 + threadIdx.x;
    if (idx >= KOUT * KD) return;
    int k = idx / KD, r = idx - k * KD;
    int t = r >> 6, c = r & 63;
    int ky = t / 3, kx = t - ky * 3;
    wp[idx] = f2bf(w[((k * CIN + c) * 3 + ky) * 3 + kx]);
}

// ---- main implicit-GEMM conv: C[kout][sp] = sum_k Wp[kout][kk] * X[kk][sp] ----
__global__ __launch_bounds__(256, 2)
void conv_mfma(const float* __restrict__ x, const unsigned short* __restrict__ wp,
               const float* __restrict__ off, float* __restrict__ out)
{
    // LDS: xs[row][c], row = staged spatial index (242), c = 64 bf16 channels.
    // ushort index = row*64 + (c ^ ((row&7)<<3))  == byte swizzle ((row&7)<<4).
    __shared__ unsigned short xs[NEXT * 64];

    const int b    = blockIdx.y;
    const int sp0  = blockIdx.x * BN;
    const int tid  = threadIdx.x;
    const int lane = tid & 63;
    const int wid  = tid >> 6;

    // ---------- stage x window: transposed + bf16 + swizzled ----------
    {
        const float* xb  = x + b * (CIN * SP);
        const int    cw0 = wid * 16;                 // 16 channels per wave
        #pragma unroll
        for (int q = 0; q < 4; ++q) {                // 4 channels per iter
            const int c = cw0 + q * 4;
            const float* xc0 = xb + c * SP;
            #pragma unroll
            for (int rb = 0; rb < 4; ++rb) {
                const int r = rb * 64 + lane;
                if (r < NEXT) {
                    int spg = sp0 - HALO + r;
                    spg = min(max(spg, 0), SP - 1);  // clamp; invalid taps masked later
                    ushort4_t u;
                    u.x = f2bf(xc0[spg]);
                    u.y = f2bf(xc0[SP + spg]);
                    u.z = f2bf(xc0[2 * SP + spg]);
                    u.w = f2bf(xc0[3 * SP + spg]);
                    const int widx = r * 64 + (c ^ ((r & 7) << 3));
                    *(ushort4_t*)&xs[widx] = u;
                }
            }
        }
    }
    __syncthreads();

    const int wm  = (wid >> 1) * 64;   // kout offset of this wave
    const int wn  = (wid & 1) * 64;    // spatial offset of this wave
    const int l15 = lane & 15;
    const int l4  = lane >> 4;

    // ---------- per-(tap, nf) validity mask bits ----------
    unsigned long long mbits = 0ull;
    #pragma unroll
    for (int t = 0; t < 9; ++t) {
        const int dy = t / 3 - 1, dx = t % 3 - 1;
        #pragma unroll
        for (int nf = 0; nf < 4; ++nf) {
            const int n  = wn + nf * 16 + l15;
            const int sp = sp0 + n;
            const int y  = sp / HWD;
            const int xc = sp - y * HWD;
            const bool v = ((unsigned)(y + dy) < (unsigned)HWD) &
                           ((unsigned)(xc + dx) < (unsigned)HWD);
            mbits |= (unsigned long long)(v ? 1 : 0) << (t * 4 + nf);
        }
    }

    // ---------- A (weight) fragment base addresses ----------
    const unsigned short* abase[4];
    #pragma unroll
    for (int mi = 0; mi < 4; ++mi)
        abase[mi] = wp + (wm + 16 * mi + l15) * KD + 8 * l4;

    f32x4 acc[4][4] = {};              // [mi][nf]
    const frag_t zf = {0,0,0,0,0,0,0,0};
    const int cread = 8 * l4;

    // ---------- K loop: 9 taps x 2 channel-chunks, no barriers ----------
    #pragma unroll
    for (int t = 0; t < 9; ++t) {
        const int s    = (t / 3 - 1) * HWD + (t % 3 - 1);  // 1D shift
        const int row0 = wn + l15 + HALO + s;
        const int sw   = (row0 & 7) << 3;
        #pragma unroll
        for (int ch = 0; ch < 2; ++ch) {
            const int c0 = ch * 32;
            const int kc = t * 2 + ch;
            frag_t a[4], bfr[4];
            #pragma unroll
            for (int mi = 0; mi < 4; ++mi)
                a[mi] = *(const frag_t*)(abase[mi] + kc * 32);
            #pragma unroll
            for (int nf = 0; nf < 4; ++nf) {
                const frag_t bl = *(const frag_t*)&xs[(row0 + 16 * nf) * 64
                                                     + ((c0 + cread) ^ sw)];
                const bool v = (mbits >> (t * 4 + nf)) & 1;
                bfr[nf] = v ? bl : zf;
            }
            #pragma unroll
            for (int mi = 0; mi < 4; ++mi)
                #pragma unroll
                for (int nf = 0; nf < 4; ++nf)
                    acc[mi][nf] = __builtin_amdgcn_mfma_f32_16x16x32_bf16(
                        a[mi], bfr[nf], acc[mi][nf], 0, 0, 0);
        }
    }

    // ---------- epilogue: C[m][n]: n = lane&15 (spatial), m = 4*(lane>>4)+reg ----------
    const int spn = sp0 + wn + l15;
    #pragma unroll
    for (int mi = 0; mi < 4; ++mi) {
        const int km = wm + 16 * mi + 4 * l4;
        #pragma unroll
        for (int reg = 0; reg < 4; ++reg) {
            const int  kk  = km + reg;
            const float ofv = off[kk];
            float* ob = out + (b * KOUT + kk) * SP;
            #pragma unroll
            for (int nf = 0; nf < 4; ++nf) {
                const int sp = spn + 16 * nf;
                if (sp < SP) ob[sp] = acc[mi][nf][reg] + ofv;
            }
        }
    }
}

// ---- fallback (ws too small): round-1 fp32 direct conv ----
__global__ __launch_bounds__(256)
void conv3x3_kernel(const float* __restrict__ x, const float* __restrict__ w,
                    const float* __restrict__ off, float* __restrict__ out)
{
    const int s  = blockIdx.x * 256 + threadIdx.x;
    const int b  = s / SP;
    const int sp = s - b * SP;
    const int y  = sp / HWD;
    const int xx = sp - y * HWD;
    const int k0 = blockIdx.y * 4;

    const int   xm1 = (xx > 0) ? xx - 1 : 0;
    const int   xp1 = (xx < HWD - 1) ? xx + 1 : HWD - 1;
    const float m0  = (xx > 0) ? 1.f : 0.f;
    const float m2  = (xx < HWD - 1) ? 1.f : 0.f;

    int ro[3]; float msk[3][3];
    #pragma unroll
    for (int ky = 0; ky < 3; ++ky) {
        const int  yy = y + ky - 1;
        const bool ok = (unsigned)yy < (unsigned)HWD;
        const float rm = ok ? 1.f : 0.f;
        ro[ky] = (ok ? yy : 0) * HWD;
        msk[ky][0] = rm * m0; msk[ky][1] = rm; msk[ky][2] = rm * m2;
    }
    float acc[4] = {0.f, 0.f, 0.f, 0.f};
    const float* xb = x + b * (CIN * SP);
    for (int c = 0; c < CIN; ++c) {
        const float* xc = xb + c * SP;
        #pragma unroll
        for (int ky = 0; ky < 3; ++ky) {
            const float* xr = xc + ro[ky];
            const float v0 = xr[xm1] * msk[ky][0];
            const float v1 = xr[xx]  * msk[ky][1];
            const float v2 = xr[xp1] * msk[ky][2];
            const int wi = c * 9 + ky * 3;
            #pragma unroll
            for (int kk = 0; kk < 4; ++kk) {
                const float* wr = w + (k0 + kk) * (CIN * 9) + wi;
                acc[kk] = fmaf(v0, wr[0], acc[kk]);
                acc[kk] = fmaf(v1, wr[1], acc[kk]);
                acc[kk] = fmaf(v2, wr[2], acc[kk]);
            }
        }
    }
    #pragma unroll
    for (int kk = 0; kk < 4; ++kk)
        out[(b * KOUT + k0 + kk) * SP + sp] = acc[kk] + off[k0 + kk];
}

} // namespace

extern "C" void kernel_launch(void* const* d_in, const int* in_sizes, int n_in,
                              void* d_out, int out_size, void* d_ws, size_t ws_size,
                              hipStream_t stream)
{
    const float* x   = (const float*)d_in[0];
    const float* w   = (const float*)d_in[1];
    const float* off = (const float*)d_in[2];
    float* out = (float*)d_out;

    if (ws_size >= (size_t)(KOUT * KD * 2)) {
        unsigned short* wpd = (unsigned short*)d_ws;
        wconv_kernel<<<(KOUT * KD + 255) / 256, 256, 0, stream>>>(w, wpd);
        dim3 grid(NTILES, BATCH);
        conv_mfma<<<grid, dim3(256, 1, 1), 0, stream>>>(x, wpd, off, out);
    } else {
        dim3 grid((BATCH * SP) / 256, KOUT / 4);
        conv3x3_kernel<<<grid, dim3(256, 1, 1), 0, stream>>>(x, w, off, out);
    }
}

// Round 3
// 45.163 us; speedup vs baseline: 6.9328x; 1.6942x over previous
//
#include <hip/hip_runtime.h>
#include <hip/hip_bf16.h>

namespace {

using frag_t    = __attribute__((ext_vector_type(8))) short;   // 8 bf16 = 16 B
using f32x4     = __attribute__((ext_vector_type(4))) float;   // MFMA acc
using float4_t  = __attribute__((ext_vector_type(4))) float;

constexpr int BATCH = 32;
constexpr int CIN   = 64;
constexpr int HWD   = 56;
constexpr int KOUT  = 128;
constexpr int SP    = HWD * HWD;        // 3136 = 49*64
constexpr int KD    = 9 * CIN;          // 576
constexpr int BN    = 128;              // spatial tile per block
constexpr int HALO  = 57;
constexpr int NEXT  = BN + 2 * HALO;    // 242 staged rows
constexpr int NTILES= SP / BN + 1;      // 25
constexpr int TT    = BATCH * (SP / 64);            // 1568 transpose blocks
constexpr int WB    = (KOUT * KD + 255) / 256;      // 288 weight-repack blocks

__device__ inline unsigned short f2bf(float f) {
    __hip_bfloat16 h = __float2bfloat16(f);
    return __builtin_bit_cast(unsigned short, h);
}

// ---- prep: (a) transpose x -> xT[b][sp][c] bf16; (b) repack w -> wpA[kc][kout][32] ----
__global__ __launch_bounds__(256)
void prep_kernel(const float* __restrict__ x, const float* __restrict__ w,
                 unsigned short* __restrict__ wpA, unsigned short* __restrict__ xT)
{
    if (blockIdx.x >= TT) {
        // weight repack: kk = t*64 + c (t = ky*3+kx); chunk kc = kk>>5, e = kk&31.
        // wpA[(kc*KOUT + kout)*32 + e] -> per-wave A-frag loads are 1 KB contiguous.
        const int idx = (blockIdx.x - TT) * 256 + threadIdx.x;
        if (idx < KOUT * KD) {
            const int kout = idx / KD, kk = idx - kout * KD;
            const int kc = kk >> 5, e = kk & 31;
            const int t = kk >> 6, c = kk & 63;
            const int ky = t / 3, kx = t - ky * 3;
            wpA[(kc * KOUT + kout) * 32 + e] = f2bf(w[((kout * CIN + c) * 3 + ky) * 3 + kx]);
        }
        return;
    }
    // transpose one 64-sp x 64-ch tile of one image
    __shared__ float ls[64][68];                    // pad 68: rows 16B-aligned
    const int bb   = blockIdx.x / (SP / 64);
    const int tile = blockIdx.x - bb * (SP / 64);
    const int sp0  = tile * 64;
    const int tid  = threadIdx.x;
    const int cq   = tid >> 4;
    const int spo  = (tid & 15) * 4;
    const float* xb = x + (size_t)bb * CIN * SP;
    #pragma unroll
    for (int j = 0; j < 4; ++j) {
        const int c = cq + 16 * j;
        float4_t v = *(const float4_t*)&xb[(size_t)c * SP + sp0 + spo];
        ls[spo + 0][c] = v.x; ls[spo + 1][c] = v.y;
        ls[spo + 2][c] = v.z; ls[spo + 3][c] = v.w;
    }
    __syncthreads();
    unsigned short* xo = xT + (size_t)(bb * SP + sp0) * 64;
    #pragma unroll
    for (int j = 0; j < 2; ++j) {
        const int s  = tid + 256 * j;               // 512 slots: 64 sp x 8 slots
        const int sp = s >> 3, e = s & 7;
        frag_t u;
        #pragma unroll
        for (int q = 0; q < 8; ++q)
            u[q] = (short)f2bf(ls[sp][e * 8 + q]);
        *(frag_t*)&xo[sp * 64 + e * 8] = u;         // 1 KB contiguous per wave
    }
}

// ---- main implicit-GEMM conv ----
__global__ __launch_bounds__(256, 2)
void conv_mfma(const unsigned short* __restrict__ xT, const unsigned short* __restrict__ wpA,
               const float* __restrict__ off, float* __restrict__ out)
{
    // xs[row][c] bf16, swizzled: ushort idx = r*64 + (c ^ ((r&7)<<3))
    __shared__ unsigned short xs[NEXT * 64];

    const int b    = blockIdx.y;
    const int sp0  = blockIdx.x * BN;
    const int tid  = threadIdx.x;
    const int lane = tid & 63;
    const int wid  = tid >> 6;

    // ---------- stage window from xT: linear 16B loads, swizzled b128 writes ----------
    {
        const unsigned short* xb = xT + (size_t)b * SP * 64;
        #pragma unroll
        for (int it = 0; it < 8; ++it) {
            const int s = it * 256 + tid;           // 1936 slots (242 rows x 8)
            if (s < NEXT * 8) {
                const int r = s >> 3, e = s & 7;
                int g = sp0 - HALO + r;
                g = min(max(g, 0), SP - 1);         // clamp; invalid taps masked below
                frag_t v = *(const frag_t*)&xb[(size_t)g * 64 + e * 8];
                *(frag_t*)&xs[r * 64 + ((e * 8) ^ ((r & 7) << 3))] = v;
            }
        }
    }
    __syncthreads();

    const int wm  = (wid >> 1) * 64;   // kout offset of this wave
    const int wn  = (wid & 1) * 64;    // spatial offset of this wave
    const int l15 = lane & 15;
    const int l4  = lane >> 4;

    // ---------- per-(tap, nf) validity mask bits ----------
    unsigned long long mbits = 0ull;
    #pragma unroll
    for (int t = 0; t < 9; ++t) {
        const int dy = t / 3 - 1, dx = t % 3 - 1;
        #pragma unroll
        for (int nf = 0; nf < 4; ++nf) {
            const int sp = sp0 + wn + nf * 16 + l15;
            const int y  = sp / HWD;
            const int xc = sp - y * HWD;
            const bool v = ((unsigned)(y + dy) < (unsigned)HWD) &
                           ((unsigned)(xc + dx) < (unsigned)HWD);
            mbits |= (unsigned long long)(v ? 1 : 0) << (t * 4 + nf);
        }
    }

    // A-frag base: wave reads 1 KB contiguous per (kc, mi)
    const unsigned short* abase = wpA + (wm + l15) * 32 + 8 * l4;

    f32x4 acc[4][4] = {};              // [mi][nf]
    const frag_t zf = {0,0,0,0,0,0,0,0};
    const int cread = 8 * l4;

    // ---------- K loop: 18 chunks, no barriers ----------
    #pragma unroll
    for (int kc = 0; kc < 18; ++kc) {
        const int t  = kc >> 1;
        const int c0 = (kc & 1) * 32;
        const int s    = (t / 3 - 1) * HWD + (t % 3 - 1);
        const int row0 = wn + l15 + HALO + s;
        const int sw   = (row0 & 7) << 3;
        frag_t a[4], bfr[4];
        #pragma unroll
        for (int mi = 0; mi < 4; ++mi)
            a[mi] = *(const frag_t*)(abase + kc * (KOUT * 32) + mi * (16 * 32));
        #pragma unroll
        for (int nf = 0; nf < 4; ++nf) {
            const frag_t bl = *(const frag_t*)&xs[(row0 + 16 * nf) * 64
                                                 + ((c0 + cread) ^ sw)];
            const bool v = (mbits >> (t * 4 + nf)) & 1;
            bfr[nf] = v ? bl : zf;
        }
        #pragma unroll
        for (int mi = 0; mi < 4; ++mi)
            #pragma unroll
            for (int nf = 0; nf < 4; ++nf)
                acc[mi][nf] = __builtin_amdgcn_mfma_f32_16x16x32_bf16(
                    a[mi], bfr[nf], acc[mi][nf], 0, 0, 0);
    }

    // ---------- epilogue ----------
    const int spn = sp0 + wn + l15;
    #pragma unroll
    for (int mi = 0; mi < 4; ++mi) {
        const int km = wm + 16 * mi + 4 * l4;
        #pragma unroll
        for (int reg = 0; reg < 4; ++reg) {
            const int  kk  = km + reg;
            const float ofv = off[kk];
            float* ob = out + (size_t)(b * KOUT + kk) * SP;
            #pragma unroll
            for (int nf = 0; nf < 4; ++nf) {
                const int sp = spn + 16 * nf;
                if (sp < SP) ob[sp] = acc[mi][nf][reg] + ofv;
            }
        }
    }
}

// ---- fallback: round-1 fp32 direct conv ----
__global__ __launch_bounds__(256)
void conv3x3_kernel(const float* __restrict__ x, const float* __restrict__ w,
                    const float* __restrict__ off, float* __restrict__ out)
{
    const int s  = blockIdx.x * 256 + threadIdx.x;
    const int b  = s / SP;
    const int sp = s - b * SP;
    const int y  = sp / HWD;
    const int xx = sp - y * HWD;
    const int k0 = blockIdx.y * 4;

    const int   xm1 = (xx > 0) ? xx - 1 : 0;
    const int   xp1 = (xx < HWD - 1) ? xx + 1 : HWD - 1;
    const float m0  = (xx > 0) ? 1.f : 0.f;
    const float m2  = (xx < HWD - 1) ? 1.f : 0.f;

    int ro[3]; float msk[3][3];
    #pragma unroll
    for (int ky = 0; ky < 3; ++ky) {
        const int  yy = y + ky - 1;
        const bool ok = (unsigned)yy < (unsigned)HWD;
        const float rm = ok ? 1.f : 0.f;
        ro[ky] = (ok ? yy : 0) * HWD;
        msk[ky][0] = rm * m0; msk[ky][1] = rm; msk[ky][2] = rm * m2;
    }
    float acc[4] = {0.f, 0.f, 0.f, 0.f};
    const float* xb = x + (size_t)b * CIN * SP;
    for (int c = 0; c < CIN; ++c) {
        const float* xc = xb + (size_t)c * SP;
        #pragma unroll
        for (int ky = 0; ky < 3; ++ky) {
            const float* xr = xc + ro[ky];
            const float v0 = xr[xm1] * msk[ky][0];
            const float v1 = xr[xx]  * msk[ky][1];
            const float v2 = xr[xp1] * msk[ky][2];
            const int wi = c * 9 + ky * 3;
            #pragma unroll
            for (int kk = 0; kk < 4; ++kk) {
                const float* wr = w + (size_t)(k0 + kk) * (CIN * 9) + wi;
                acc[kk] = fmaf(v0, wr[0], acc[kk]);
                acc[kk] = fmaf(v1, wr[1], acc[kk]);
                acc[kk] = fmaf(v2, wr[2], acc[kk]);
            }
        }
    }
    #pragma unroll
    for (int kk = 0; kk < 4; ++kk)
        out[(size_t)(b * KOUT + k0 + kk) * SP + sp] = acc[kk] + off[k0 + kk];
}

} // namespace

extern "C" void kernel_launch(void* const* d_in, const int* in_sizes, int n_in,
                              void* d_out, int out_size, void* d_ws, size_t ws_size,
                              hipStream_t stream)
{
    const float* x   = (const float*)d_in[0];
    const float* w   = (const float*)d_in[1];
    const float* off = (const float*)d_in[2];
    float* out = (float*)d_out;

    const size_t wpa_bytes = (size_t)KOUT * KD * 2;          // 147456
    const size_t xt_bytes  = (size_t)BATCH * SP * CIN * 2;   // 12845056

    if (ws_size >= wpa_bytes + xt_bytes) {
        unsigned short* wpA = (unsigned short*)d_ws;
        unsigned short* xT  = (unsigned short*)((char*)d_ws + wpa_bytes);
        prep_kernel<<<TT + WB, 256, 0, stream>>>(x, w, wpA, xT);
        dim3 grid(NTILES, BATCH);
        conv_mfma<<<grid, dim3(256, 1, 1), 0, stream>>>(xT, wpA, off, out);
    } else {
        dim3 grid((BATCH * SP) / 256, KOUT / 4);
        conv3x3_kernel<<<grid, dim3(256, 1, 1), 0, stream>>>(x, w, off, out);
    }
}

// Round 4
// 44.112 us; speedup vs baseline: 7.0981x; 1.0238x over previous
//
#include <hip/hip_runtime.h>
#include <hip/hip_bf16.h>

namespace {

using frag_t    = __attribute__((ext_vector_type(8))) short;   // 8 bf16 = 16 B
using f32x4     = __attribute__((ext_vector_type(4))) float;   // MFMA acc
using float4_t  = __attribute__((ext_vector_type(4))) float;

constexpr int BATCH = 32;
constexpr int CIN   = 64;
constexpr int HWD   = 56;
constexpr int KOUT  = 128;
constexpr int SP    = HWD * HWD;        // 3136 = 49*64
constexpr int KD    = 9 * CIN;          // 576
constexpr int BN    = 128;              // spatial tile per block
constexpr int HALO  = 57;
constexpr int NEXT  = BN + 2 * HALO;    // 242 staged rows
constexpr int NTILES= SP / BN + 1;      // 25
constexpr int NWG   = NTILES * BATCH;   // 800 conv blocks (= 8 XCDs * 100)
constexpr int TT    = BATCH * (SP / 64);            // 1568 transpose blocks
constexpr int WB    = (KOUT * KD + 255) / 256;      // weight-repack blocks

__device__ inline unsigned short f2bf(float f) {
    __hip_bfloat16 h = __float2bfloat16(f);
    return __builtin_bit_cast(unsigned short, h);
}

// ---- prep: (a) transpose x -> xT[b][sp][c] bf16; (b) repack w -> wpA[kc][kout][32] ----
__global__ __launch_bounds__(256)
void prep_kernel(const float* __restrict__ x, const float* __restrict__ w,
                 unsigned short* __restrict__ wpA, unsigned short* __restrict__ xT)
{
    if (blockIdx.x >= TT) {
        const int idx = (blockIdx.x - TT) * 256 + threadIdx.x;
        if (idx < KOUT * KD) {
            const int kout = idx / KD, kk = idx - kout * KD;
            const int kc = kk >> 5, e = kk & 31;
            const int t = kk >> 6, c = kk & 63;
            const int ky = t / 3, kx = t - ky * 3;
            wpA[(kc * KOUT + kout) * 32 + e] = f2bf(w[((kout * CIN + c) * 3 + ky) * 3 + kx]);
        }
        return;
    }
    __shared__ float ls[64][68];
    const int bb   = blockIdx.x / (SP / 64);
    const int tile = blockIdx.x - bb * (SP / 64);
    const int sp0  = tile * 64;
    const int tid  = threadIdx.x;
    const int cq   = tid >> 4;
    const int spo  = (tid & 15) * 4;
    const float* xb = x + (size_t)bb * CIN * SP;
    #pragma unroll
    for (int j = 0; j < 4; ++j) {
        const int c = cq + 16 * j;
        float4_t v = *(const float4_t*)&xb[(size_t)c * SP + sp0 + spo];
        ls[spo + 0][c] = v.x; ls[spo + 1][c] = v.y;
        ls[spo + 2][c] = v.z; ls[spo + 3][c] = v.w;
    }
    __syncthreads();
    unsigned short* xo = xT + (size_t)(bb * SP + sp0) * 64;
    #pragma unroll
    for (int j = 0; j < 2; ++j) {
        const int s  = tid + 256 * j;
        const int sp = s >> 3, e = s & 7;
        frag_t u;
        #pragma unroll
        for (int q = 0; q < 8; ++q)
            u[q] = (short)f2bf(ls[sp][e * 8 + q]);
        *(frag_t*)&xo[sp * 64 + e * 8] = u;
    }
}

// ---- main implicit-GEMM conv, software-pipelined fragment loads ----
__global__ __launch_bounds__(256, 2)
void conv_mfma(const unsigned short* __restrict__ xT, const unsigned short* __restrict__ wpA,
               const float* __restrict__ off, float* __restrict__ out)
{
    __shared__ unsigned short xs[NEXT * 64];   // [row][c] swizzled: c ^ ((r&7)<<3)

    // XCD-aware swizzle: dispatch id d -> work id; XCD (d&7) owns a contiguous
    // run of 100 work ids = 4 complete images -> halo re-reads hit that XCD's L2.
    const int d    = blockIdx.x;
    const int wk   = (d & 7) * (NWG / 8) + (d >> 3);
    const int b    = wk / NTILES;
    const int sp0  = (wk - b * NTILES) * BN;
    const int tid  = threadIdx.x;
    const int lane = tid & 63;
    const int wid  = tid >> 6;

    // ---------- stage window from xT ----------
    {
        const unsigned short* xb = xT + (size_t)b * SP * 64;
        #pragma unroll
        for (int it = 0; it < 8; ++it) {
            const int s = it * 256 + tid;           // 1936 slots (242 rows x 8)
            if (s < NEXT * 8) {
                const int r = s >> 3, e = s & 7;
                int g = sp0 - HALO + r;
                g = min(max(g, 0), SP - 1);
                frag_t v = *(const frag_t*)&xb[(size_t)g * 64 + e * 8];
                *(frag_t*)&xs[r * 64 + ((e * 8) ^ ((r & 7) << 3))] = v;
            }
        }
    }
    __syncthreads();

    const int wm  = (wid >> 1) * 64;
    const int wn  = (wid & 1) * 64;
    const int l15 = lane & 15;
    const int l4  = lane >> 4;

    // ---------- per-(tap, nf) validity masks ----------
    unsigned long long mbits = 0ull;
    #pragma unroll
    for (int t = 0; t < 9; ++t) {
        const int dy = t / 3 - 1, dx = t % 3 - 1;
        #pragma unroll
        for (int nf = 0; nf < 4; ++nf) {
            const int sp = sp0 + wn + nf * 16 + l15;
            const int y  = sp / HWD;
            const int xc = sp - y * HWD;
            const bool v = ((unsigned)(y + dy) < (unsigned)HWD) &
                           ((unsigned)(xc + dx) < (unsigned)HWD);
            mbits |= (unsigned long long)(v ? 1 : 0) << (t * 4 + nf);
        }
    }

    const unsigned short* abase = wpA + (wm + l15) * 32 + 8 * l4;
    const int cread = 8 * l4;
    const frag_t zf = {0,0,0,0,0,0,0,0};

    auto load_a = [&](frag_t dst[4], int kc) {
        #pragma unroll
        for (int mi = 0; mi < 4; ++mi)
            dst[mi] = *(const frag_t*)(abase + kc * (KOUT * 32) + mi * (16 * 32));
    };
    auto load_b = [&](frag_t dst[4], int kc) {
        const int t  = kc >> 1;
        const int c0 = (kc & 1) * 32;
        const int s    = (t / 3 - 1) * HWD + (t % 3 - 1);
        const int row0 = wn + l15 + HALO + s;
        const int sw   = (row0 & 7) << 3;
        #pragma unroll
        for (int nf = 0; nf < 4; ++nf) {
            const frag_t bl = *(const frag_t*)&xs[(row0 + 16 * nf) * 64
                                                 + ((c0 + cread) ^ sw)];
            dst[nf] = ((mbits >> (t * 4 + nf)) & 1) ? bl : zf;
        }
    };

    f32x4 acc[4][4] = {};
    // software pipeline: A 2-deep, B 1-deep (all indices compile-time)
    frag_t a0[4], a1[4], bP[4];
    load_a(a0, 0);
    load_a(a1, 1);
    load_b(bP, 0);

    #pragma unroll
    for (int kc = 0; kc < 18; ++kc) {
        frag_t aC[4], bC[4];
        #pragma unroll
        for (int mi = 0; mi < 4; ++mi) { aC[mi] = a0[mi]; a0[mi] = a1[mi]; }
        #pragma unroll
        for (int nf = 0; nf < 4; ++nf) { bC[nf] = bP[nf]; }
        if (kc + 2 < 18) load_a(a1, kc + 2);
        if (kc + 1 < 18) load_b(bP, kc + 1);
        #pragma unroll
        for (int mi = 0; mi < 4; ++mi)
            #pragma unroll
            for (int nf = 0; nf < 4; ++nf)
                acc[mi][nf] = __builtin_amdgcn_mfma_f32_16x16x32_bf16(
                    aC[mi], bC[nf], acc[mi][nf], 0, 0, 0);
    }

    // ---------- epilogue ----------
    const int spn = sp0 + wn + l15;
    #pragma unroll
    for (int mi = 0; mi < 4; ++mi) {
        const int km = wm + 16 * mi + 4 * l4;
        #pragma unroll
        for (int reg = 0; reg < 4; ++reg) {
            const int  kk  = km + reg;
            const float ofv = off[kk];
            float* ob = out + (size_t)(b * KOUT + kk) * SP;
            #pragma unroll
            for (int nf = 0; nf < 4; ++nf) {
                const int sp = spn + 16 * nf;
                if (sp < SP) ob[sp] = acc[mi][nf][reg] + ofv;
            }
        }
    }
}

// ---- fallback: round-1 fp32 direct conv ----
__global__ __launch_bounds__(256)
void conv3x3_kernel(const float* __restrict__ x, const float* __restrict__ w,
                    const float* __restrict__ off, float* __restrict__ out)
{
    const int s  = blockIdx.x * 256 + threadIdx.x;
    const int b  = s / SP;
    const int sp = s - b * SP;
    const int y  = sp / HWD;
    const int xx = sp - y * HWD;
    const int k0 = blockIdx.y * 4;

    const int   xm1 = (xx > 0) ? xx - 1 : 0;
    const int   xp1 = (xx < HWD - 1) ? xx + 1 : HWD - 1;
    const float m0  = (xx > 0) ? 1.f : 0.f;
    const float m2  = (xx < HWD - 1) ? 1.f : 0.f;

    int ro[3]; float msk[3][3];
    #pragma unroll
    for (int ky = 0; ky < 3; ++ky) {
        const int  yy = y + ky - 1;
        const bool ok = (unsigned)yy < (unsigned)HWD;
        const float rm = ok ? 1.f : 0.f;
        ro[ky] = (ok ? yy : 0) * HWD;
        msk[ky][0] = rm * m0; msk[ky][1] = rm; msk[ky][2] = rm * m2;
    }
    float acc[4] = {0.f, 0.f, 0.f, 0.f};
    const float* xb = x + (size_t)b * CIN * SP;
    for (int c = 0; c < CIN; ++c) {
        const float* xc = xb + (size_t)c * SP;
        #pragma unroll
        for (int ky = 0; ky < 3; ++ky) {
            const float* xr = xc + ro[ky];
            const float v0 = xr[xm1] * msk[ky][0];
            const float v1 = xr[xx]  * msk[ky][1];
            const float v2 = xr[xp1] * msk[ky][2];
            const int wi = c * 9 + ky * 3;
            #pragma unroll
            for (int kk = 0; kk < 4; ++kk) {
                const float* wr = w + (size_t)(k0 + kk) * (CIN * 9) + wi;
                acc[kk] = fmaf(v0, wr[0], acc[kk]);
                acc[kk] = fmaf(v1, wr[1], acc[kk]);
                acc[kk] = fmaf(v2, wr[2], acc[kk]);
            }
        }
    }
    #pragma unroll
    for (int kk = 0; kk < 4; ++kk)
        out[(size_t)(b * KOUT + k0 + kk) * SP + sp] = acc[kk] + off[k0 + kk];
}

} // namespace

extern "C" void kernel_launch(void* const* d_in, const int* in_sizes, int n_in,
                              void* d_out, int out_size, void* d_ws, size_t ws_size,
                              hipStream_t stream)
{
    const float* x   = (const float*)d_in[0];
    const float* w   = (const float*)d_in[1];
    const float* off = (const float*)d_in[2];
    float* out = (float*)d_out;

    const size_t wpa_bytes = (size_t)KOUT * KD * 2;          // 147456
    const size_t xt_bytes  = (size_t)BATCH * SP * CIN * 2;   // 12845056

    if (ws_size >= wpa_bytes + xt_bytes) {
        unsigned short* wpA = (unsigned short*)d_ws;
        unsigned short* xT  = (unsigned short*)((char*)d_ws + wpa_bytes);
        prep_kernel<<<TT + WB, 256, 0, stream>>>(x, w, wpA, xT);
        conv_mfma<<<NWG, dim3(256, 1, 1), 0, stream>>>(xT, wpA, off, out);
    } else {
        dim3 grid((BATCH * SP) / 256, KOUT / 4);
        conv3x3_kernel<<<grid, dim3(256, 1, 1), 0, stream>>>(x, w, off, out);
    }
}

// Round 5
// 43.718 us; speedup vs baseline: 7.1619x; 1.0090x over previous
//
#include <hip/hip_runtime.h>
#include <hip/hip_bf16.h>

namespace {

using frag_t    = __attribute__((ext_vector_type(8))) short;   // 8 bf16 = 16 B
using f32x4     = __attribute__((ext_vector_type(4))) float;   // MFMA acc
using float4_t  = __attribute__((ext_vector_type(4))) float;

constexpr int BATCH = 32;
constexpr int CIN   = 64;
constexpr int HWD   = 56;
constexpr int KOUT  = 128;
constexpr int SP    = HWD * HWD;        // 3136
constexpr int KD    = 9 * CIN;          // 576
constexpr int BN    = 128;              // spatial tile
constexpr int HALO  = 57;
constexpr int NEXT  = BN + 2 * HALO;    // 242 staged rows
constexpr int NTILES= SP / BN + 1;      // 25
constexpr int NWG2  = NTILES * BATCH * 2;  // 1600 conv blocks (tile x kout-half)
constexpr int TT    = BATCH * (SP / 64);
constexpr int WB    = (KOUT * KD + 255) / 256;

__device__ inline unsigned short f2bf(float f) {
    __hip_bfloat16 h = __float2bfloat16(f);
    return __builtin_bit_cast(unsigned short, h);
}

// ---- prep: (a) transpose x -> xT[b][sp][c] bf16; (b) repack w -> wpA[kc][kout][32] ----
__global__ __launch_bounds__(256)
void prep_kernel(const float* __restrict__ x, const float* __restrict__ w,
                 unsigned short* __restrict__ wpA, unsigned short* __restrict__ xT)
{
    if (blockIdx.x >= TT) {
        const int idx = (blockIdx.x - TT) * 256 + threadIdx.x;
        if (idx < KOUT * KD) {
            const int kout = idx / KD, kk = idx - kout * KD;
            const int kc = kk >> 5, e = kk & 31;
            const int t = kk >> 6, c = kk & 63;
            const int ky = t / 3, kx = t - ky * 3;
            wpA[(kc * KOUT + kout) * 32 + e] = f2bf(w[((kout * CIN + c) * 3 + ky) * 3 + kx]);
        }
        return;
    }
    __shared__ float ls[64][68];
    const int bb   = blockIdx.x / (SP / 64);
    const int tile = blockIdx.x - bb * (SP / 64);
    const int sp0  = tile * 64;
    const int tid  = threadIdx.x;
    const int cq   = tid >> 4;
    const int spo  = (tid & 15) * 4;
    const float* xb = x + (size_t)bb * CIN * SP;
    #pragma unroll
    for (int j = 0; j < 4; ++j) {
        const int c = cq + 16 * j;
        float4_t v = *(const float4_t*)&xb[(size_t)c * SP + sp0 + spo];
        ls[spo + 0][c] = v.x; ls[spo + 1][c] = v.y;
        ls[spo + 2][c] = v.z; ls[spo + 3][c] = v.w;
    }
    __syncthreads();
    unsigned short* xo = xT + (size_t)(bb * SP + sp0) * 64;
    #pragma unroll
    for (int j = 0; j < 2; ++j) {
        const int s  = tid + 256 * j;
        const int sp = s >> 3, e = s & 7;
        frag_t u;
        #pragma unroll
        for (int q = 0; q < 8; ++q)
            u[q] = (short)f2bf(ls[sp][e * 8 + q]);
        *(frag_t*)&xo[sp * 64 + e * 8] = u;
    }
}

// ---- main implicit-GEMM conv: kout-split blocks + global_load_lds staging ----
__global__ __launch_bounds__(256, 4)
void conv_mfma(const unsigned short* __restrict__ xT, const unsigned short* __restrict__ wpA,
               const float* __restrict__ off, float* __restrict__ out)
{
    // xs[row][c] bf16; LDS holds xT[g(r)][z ^ sw(r)] at slot [r][z]  (sw(r) = (r&7)<<3)
    // -> read with  xs[r*64 + (c ^ sw(r))]  == xT[g(r)][c].  (both-sides swizzle, src-side)
    __shared__ unsigned short xs[NEXT * 64];

    // XCD swizzle (1600 = 8*200, bijective). Adjacent wk pairs = same tile, kh=0/1.
    const int d    = blockIdx.x;
    const int wk   = (d & 7) * (NWG2 / 8) + (d >> 3);
    const int kh   = wk & 1;
    const int wk2  = wk >> 1;
    const int b    = wk2 / NTILES;
    const int sp0  = (wk2 - b * NTILES) * BN;
    const int tid  = threadIdx.x;
    const int lane = tid & 63;
    const int wid  = tid >> 6;

    // ---------- stage window: direct global->LDS, pre-swizzled source ----------
    {
        const unsigned short* xb = xT + (size_t)b * SP * 64;
        // per-lane source swizzle within a 128B row (r&7 == lane>>3 since R0 % 8 == 0)
        const int lsw = ((lane & 7) * 8) ^ ((lane >> 3) << 3);
        #pragma unroll
        for (int it = 0; it < 8; ++it) {
            const int R0 = it * 32 + wid * 8;       // wave-uniform base row
            const int r  = R0 + (lane >> 3);
            if (r < NEXT) {
                int g = sp0 - HALO + r;
                g = min(max(g, 0), SP - 1);
                const unsigned short* src = xb + (size_t)g * 64 + lsw;
                __builtin_amdgcn_global_load_lds(
                    (const __attribute__((address_space(1))) unsigned int*)src,
                    (__attribute__((address_space(3))) unsigned int*)&xs[R0 * 64 + (lane) * 8],
                    16, 0, 0);
            }
        }
    }
    asm volatile("s_waitcnt vmcnt(0)" ::: "memory");
    __syncthreads();

    const int wmL = (wid >> 1) * 32;   // local kout offset: 0 or 32
    const int wn  = (wid & 1) * 64;    // spatial offset
    const int l15 = lane & 15;
    const int l4  = lane >> 4;

    // ---------- per-(tap, nf) validity masks ----------
    unsigned long long mbits = 0ull;
    #pragma unroll
    for (int t = 0; t < 9; ++t) {
        const int dy = t / 3 - 1, dx = t % 3 - 1;
        #pragma unroll
        for (int nf = 0; nf < 4; ++nf) {
            const int sp = sp0 + wn + nf * 16 + l15;
            const int y  = sp / HWD;
            const int xc = sp - y * HWD;
            const bool v = ((unsigned)(y + dy) < (unsigned)HWD) &
                           ((unsigned)(xc + dx) < (unsigned)HWD);
            mbits |= (unsigned long long)(v ? 1 : 0) << (t * 4 + nf);
        }
    }

    const unsigned short* abase = wpA + (size_t)(kh * 64 + wmL + l15) * 32 + 8 * l4;
    const int cread = 8 * l4;
    const frag_t zf = {0,0,0,0,0,0,0,0};

    f32x4 acc[2][4] = {};              // [mi][nf]

    #pragma unroll
    for (int kc = 0; kc < 18; ++kc) {
        const int t  = kc >> 1;
        const int c0 = (kc & 1) * 32;
        const int s    = (t / 3 - 1) * HWD + (t % 3 - 1);
        const int row0 = wn + l15 + HALO + s;
        const int sw   = (row0 & 7) << 3;
        frag_t a[2], bfr[4];
        #pragma unroll
        for (int mi = 0; mi < 2; ++mi)
            a[mi] = *(const frag_t*)(abase + (size_t)(kc * KOUT + mi * 16) * 32);
        #pragma unroll
        for (int nf = 0; nf < 4; ++nf) {
            const frag_t bl = *(const frag_t*)&xs[(row0 + 16 * nf) * 64
                                                 + ((c0 + cread) ^ sw)];
            bfr[nf] = ((mbits >> (t * 4 + nf)) & 1) ? bl : zf;
        }
        #pragma unroll
        for (int mi = 0; mi < 2; ++mi)
            #pragma unroll
            for (int nf = 0; nf < 4; ++nf)
                acc[mi][nf] = __builtin_amdgcn_mfma_f32_16x16x32_bf16(
                    a[mi], bfr[nf], acc[mi][nf], 0, 0, 0);
    }

    // ---------- epilogue ----------
    const int spn = sp0 + wn + l15;
    #pragma unroll
    for (int mi = 0; mi < 2; ++mi) {
        const int km = kh * 64 + wmL + 16 * mi + 4 * l4;
        #pragma unroll
        for (int reg = 0; reg < 4; ++reg) {
            const int  kk  = km + reg;
            const float ofv = off[kk];
            float* ob = out + (size_t)(b * KOUT + kk) * SP;
            #pragma unroll
            for (int nf = 0; nf < 4; ++nf) {
                const int sp = spn + 16 * nf;
                if (sp < SP) ob[sp] = acc[mi][nf][reg] + ofv;
            }
        }
    }
}

// ---- fallback: round-1 fp32 direct conv ----
__global__ __launch_bounds__(256)
void conv3x3_kernel(const float* __restrict__ x, const float* __restrict__ w,
                    const float* __restrict__ off, float* __restrict__ out)
{
    const int s  = blockIdx.x * 256 + threadIdx.x;
    const int b  = s / SP;
    const int sp = s - b * SP;
    const int y  = sp / HWD;
    const int xx = sp - y * HWD;
    const int k0 = blockIdx.y * 4;

    const int   xm1 = (xx > 0) ? xx - 1 : 0;
    const int   xp1 = (xx < HWD - 1) ? xx + 1 : HWD - 1;
    const float m0  = (xx > 0) ? 1.f : 0.f;
    const float m2  = (xx < HWD - 1) ? 1.f : 0.f;

    int ro[3]; float msk[3][3];
    #pragma unroll
    for (int ky = 0; ky < 3; ++ky) {
        const int  yy = y + ky - 1;
        const bool ok = (unsigned)yy < (unsigned)HWD;
        const float rm = ok ? 1.f : 0.f;
        ro[ky] = (ok ? yy : 0) * HWD;
        msk[ky][0] = rm * m0; msk[ky][1] = rm; msk[ky][2] = rm * m2;
    }
    float acc[4] = {0.f, 0.f, 0.f, 0.f};
    const float* xb = x + (size_t)b * CIN * SP;
    for (int c = 0; c < CIN; ++c) {
        const float* xc = xb + (size_t)c * SP;
        #pragma unroll
        for (int ky = 0; ky < 3; ++ky) {
            const float* xr = xc + ro[ky];
            const float v0 = xr[xm1] * msk[ky][0];
            const float v1 = xr[xx]  * msk[ky][1];
            const float v2 = xr[xp1] * msk[ky][2];
            const int wi = c * 9 + ky * 3;
            #pragma unroll
            for (int kk = 0; kk < 4; ++kk) {
                const float* wr = w + (size_t)(k0 + kk) * (CIN * 9) + wi;
                acc[kk] = fmaf(v0, wr[0], acc[kk]);
                acc[kk] = fmaf(v1, wr[1], acc[kk]);
                acc[kk] = fmaf(v2, wr[2], acc[kk]);
            }
        }
    }
    #pragma unroll
    for (int kk = 0; kk < 4; ++kk)
        out[(size_t)(b * KOUT + k0 + kk) * SP + sp] = acc[kk] + off[k0 + kk];
}

} // namespace

extern "C" void kernel_launch(void* const* d_in, const int* in_sizes, int n_in,
                              void* d_out, int out_size, void* d_ws, size_t ws_size,
                              hipStream_t stream)
{
    const float* x   = (const float*)d_in[0];
    const float* w   = (const float*)d_in[1];
    const float* off = (const float*)d_in[2];
    float* out = (float*)d_out;

    const size_t wpa_bytes = (size_t)KOUT * KD * 2;          // 147456
    const size_t xt_bytes  = (size_t)BATCH * SP * CIN * 2;   // 12845056

    if (ws_size >= wpa_bytes + xt_bytes) {
        unsigned short* wpA = (unsigned short*)d_ws;
        unsigned short* xT  = (unsigned short*)((char*)d_ws + wpa_bytes);
        prep_kernel<<<TT + WB, 256, 0, stream>>>(x, w, wpA, xT);
        conv_mfma<<<NWG2, dim3(256, 1, 1), 0, stream>>>(xT, wpA, off, out);
    } else {
        dim3 grid((BATCH * SP) / 256, KOUT / 4);
        conv3x3_kernel<<<grid, dim3(256, 1, 1), 0, stream>>>(x, w, off, out);
    }
}